// Round 15
// baseline (2359.863 us; speedup 1.0000x reference)
//
#include <hip/hip_runtime.h>

#define BB 16
#define NN 2048
#define NITERS 100

// k = log2(e)/eps, eps = 0.05
#define K2E      28.853900817779268f
#define TWO_K2E  57.707801635558536f
#define INV2K    0.017328679513998632f   // 1/(2k)
#define INV_K2E  0.034657359027997264f
#define INV4K    0.008664339756999316f   // 1/(4k)
#define LMU      (-11.0f)                // log2(1/2048)

#if __has_builtin(__builtin_amdgcn_exp2f)
#define EXP2F(x) __builtin_amdgcn_exp2f(x)
#else
#define EXP2F(x) exp2f(x)
#endif

typedef float v2f __attribute__((ext_vector_type(2)));
typedef float v4f __attribute__((ext_vector_type(4)));

// device-coherent (LLC-homed) accessors for the dual arrays
#define DSTORE(p, v) __hip_atomic_store((p), (v), __ATOMIC_RELAXED, __HIP_MEMORY_SCOPE_AGENT)
#define DLOAD(p)     __hip_atomic_load((p), __ATOMIC_RELAXED, __HIP_MEMORY_SCOPE_AGENT)

// verified multi-value butterfly: 8 partials -> full row-sum on lanes 0..7
// at row index rr = ((lane&1)<<2)|(lane&2)|((lane>>2)&1)
__device__ __forceinline__ float bfly8(const float acc[8], int lane) {
    const bool b0 = lane & 1, b1 = lane & 2, b2 = lane & 4;
    float v4[4], v2_[2], v1;
    #pragma unroll
    for (int i = 0; i < 4; ++i) {
        float recv = __shfl_xor(b0 ? acc[i] : acc[i+4], 1, 64);
        v4[i] = (b0 ? acc[i+4] : acc[i]) + recv;
    }
    #pragma unroll
    for (int i = 0; i < 2; ++i) {
        float recv = __shfl_xor(b1 ? v4[i] : v4[i+2], 2, 64);
        v2_[i] = (b1 ? v4[i+2] : v4[i]) + recv;
    }
    {
        float recv = __shfl_xor(b2 ? v2_[0] : v2_[1], 4, 64);
        v1 = (b2 ? v2_[1] : v2_[0]) + recv;
    }
    v1 += __shfl_xor(v1, 8, 64);
    v1 += __shfl_xor(v1, 16, 64);
    v1 += __shfl_xor(v1, 32, 64);
    return v1;
}

// R26 SPLIT-WAIT full-j pass: identical math and s-order to the verified
// R11 pass (bit-identical summation), but the phase-boundary wait is split
// into two half-waits consumed in order:
//   wait producers 0..7  -> stage duals[0..1024)  -> compute s=0..15
//   wait producers 8..15 -> stage duals[1024..2048) -> compute s=16..31
// The first-half compute (~3.5us) hides the second half's stragglers.
// w0-only poll (all-wave polling regressed R4/R13); barriers ~free (R14).
__device__ __forceinline__ float passH(
    const v4f* __restrict__ U, const v4f* __restrict__ T,
    const float* __restrict__ gsrc, float* __restrict__ sd,
    int* __restrict__ fb, int tgt, int rloc, int lane, int w, int tid)
{
    v2f xp0[4], xp1[4], xp2[4], acc2[4];
    #pragma unroll
    for (int p = 0; p < 4; ++p) {
        const v4f ua = U[rloc + 2*p];
        const v4f ub = U[rloc + 2*p + 1];
        xp0[p] = (v2f){ua.x * INV2K, ub.x * INV2K};
        xp1[p] = (v2f){ua.y * INV2K, ub.y * INV2K};
        xp2[p] = (v2f){ua.z * INV2K, ub.z * INV2K};
        acc2[p] = (v2f){0.f, 0.f};
    }
    #pragma unroll
    for (int hh = 0; hh < 2; ++hh) {
        // wait for the 8 producer blocks of this half, then stage their chunk
        if (w == 0) {
            for (;;) {
                int vv = (lane < 8)
                    ? __hip_atomic_load(fb + ((hh << 3) + lane) * 4,
                                        __ATOMIC_RELAXED,
                                        __HIP_MEMORY_SCOPE_AGENT)
                    : 0x7fffffff;
                if (__ballot(vv >= tgt) == ~0ULL) break;
                __builtin_amdgcn_s_sleep(1);
            }
        }
        __syncthreads();               // all waves past prior reads of sd half
        sd[(hh << 10) + tid] = DLOAD(gsrc + (hh << 10) + tid);
        __syncthreads();               // half staged
        const int sbase = hh << 4;
        #pragma unroll 4
        for (int s = sbase; s < sbase + 16; ++s) {
            const int p = lane + (s << 6);
            const v4f t = T[p];
            const float ad = sd[p];
            const v2f a0v = (v2f){t.x, t.x}, a1v = (v2f){t.y, t.y};
            const v2f a2v = (v2f){t.z, t.z}, adv = (v2f){ad, ad};
            #pragma unroll
            for (int qq = 0; qq < 4; ++qq) {
                v2f d = __builtin_elementwise_fma(xp0[qq], a0v,
                        __builtin_elementwise_fma(xp1[qq], a1v,
                        __builtin_elementwise_fma(xp2[qq], a2v, adv)));
                acc2[qq] += (v2f){EXP2F(d.x), EXP2F(d.y)};
            }
        }
    }
    float acc[8];
    #pragma unroll
    for (int p = 0; p < 4; ++p) { acc[2*p] = acc2[p].x; acc[2*p+1] = acc2[p].y; }
    return bfly8(acc, lane);   // lanes<8: full row-sum for row rloc + rr
}

// R11-verified FULL-J sum-pass (fallback kernel). UNCHANGED.
__device__ __forceinline__ float sumpassF(
    const v4f* __restrict__ U, const v4f* __restrict__ T,
    const float* __restrict__ sdv,
    int rloc, int lane)
{
    v2f xp0[4], xp1[4], xp2[4], acc2[4];
    #pragma unroll
    for (int p = 0; p < 4; ++p) {
        const v4f ua = U[rloc + 2*p];
        const v4f ub = U[rloc + 2*p + 1];
        xp0[p] = (v2f){ua.x * INV2K, ub.x * INV2K};
        xp1[p] = (v2f){ua.y * INV2K, ub.y * INV2K};
        xp2[p] = (v2f){ua.z * INV2K, ub.z * INV2K};
        acc2[p] = (v2f){0.f, 0.f};
    }
    #pragma unroll 4
    for (int s = 0; s < 32; ++s) {
        const int p = lane + (s << 6);
        const v4f t = T[p];
        const float ad = sdv[p];
        const v2f a0v = (v2f){t.x, t.x}, a1v = (v2f){t.y, t.y};
        const v2f a2v = (v2f){t.z, t.z}, adv = (v2f){ad, ad};
        #pragma unroll
        for (int qq = 0; qq < 4; ++qq) {
            v2f d = __builtin_elementwise_fma(xp0[qq], a0v,
                    __builtin_elementwise_fma(xp1[qq], a1v,
                    __builtin_elementwise_fma(xp2[qq], a2v, adv)));
            acc2[qq] += (v2f){EXP2F(d.x), EXP2F(d.y)};
        }
    }
    float acc[8];
    #pragma unroll
    for (int p = 0; p < 4; ++p) { acc[2*p] = acc2[p].x; acc[2*p+1] = acc2[p].y; }
    return bfly8(acc, lane);
}

// Epilogue partial: sum_j P_ij*C_ij, 8 rows x one j-half; AoS tables.
// (verified) — wave-local. UNCHANGED.
__device__ __forceinline__ float epilA(
    const v4f* __restrict__ U, const v4f* __restrict__ T,
    const float* __restrict__ gB,
    float Aval, int rloc, int jh, int lane)
{
    const int jb = (jh << 10) + lane;
    float dv[16];
    #pragma unroll
    for (int s = 0; s < 16; ++s)
        dv[s] = DLOAD(gB + jb + (s << 6));

    float xr0[8], xr1[8], xr2[8], Ak[8], x2k[8];
    #pragma unroll
    for (int k = 0; k < 8; ++k) {
        const v4f u = U[rloc + k];
        xr0[k] = u.x * INV2K;
        xr1[k] = u.y * INV2K;
        xr2[k] = u.z * INV2K;
        const int src = ((k & 1) << 2) | (k & 2) | ((k >> 2) & 1);
        Ak[k]  = __shfl(Aval, src, 64);
        x2k[k] = K2E * (xr0[k]*xr0[k] + xr1[k]*xr1[k] + xr2[k]*xr2[k]);
    }
    float acc = 0.f;
    for (int s = 0; s < 16; ++s) {
        const v4f t = T[jb + (s << 6)];
        const float a0 = t.x, a1 = t.y, a2 = t.z, tb = dv[s];
        const float q2 = (a0*a0 + a1*a1 + a2*a2) * INV4K;   // k|y|^2
        #pragma unroll
        for (int k = 0; k < 8; ++k) {
            float d = fmaf(xr0[k], a0, fmaf(xr1[k], a1, fmaf(xr2[k], a2, tb)));
            float P = EXP2F(d + Ak[k]);                       // exp(logP)
            float C = fmaxf((x2k[k] + q2 - (d - tb)) * INV_K2E, 0.f);
            acc = fmaf(P, C, acc);
        }
    }
    return acc;
}

// R26: R11 geometry (256 blocks x 1024 thr, batch=blk>>4, 128 rows/block,
// full-j waves, 72 KB LDS) with SPLIT-WAIT passes. Per phase:
//   passH { wait(0..7) stage-low compute-low; wait(8..15) stage-high
//           compute-high } -> POST
// POST = entry barrier (drains dual DSTOREs) + tid0 release-store.
__global__ __launch_bounds__(1024, 4) void emd_sinkhornHK(
    const float* __restrict__ x, const float* __restrict__ y,
    float* __restrict__ Af, float* __restrict__ Bf,
    int* __restrict__ flags, float* __restrict__ out)
{
    extern __shared__ float S[];     // sy(32KB) | sx(32KB) | sd(8KB) = 72 KB
    __shared__ float wsum[16];

    const int tid  = threadIdx.x;
    const int lane = tid & 63;
    const int w    = tid >> 6;        // 0..15
    const int blk  = blockIdx.x;
    const int b    = blk >> 4;        // batch 0..15
    const int q    = blk & 15;        // row-slab within batch (128 rows)
    const int base = b * NN;
    const int row0 = q * 128;
    const int rloc = row0 + w * 8;    // wave-owned 8 rows
    int* fb = flags + b * 64;         // 16 slots x 16 B per batch

    v4f   *sy = (v4f*)S;              // batch y (2k-scaled, AoS)
    v4f   *sx = (v4f*)S + NN;         // batch x
    float *sd = (float*)((v4f*)S + 2 * NN);   // staged duals [NN]

    // ---- prologue: stage 2k-scaled AoS tables for own batch ----
    #pragma unroll
    for (int v = 0; v < 2; ++v) {
        const int p = tid + (v << 10);
        const float* px = x + 3 * (size_t)(base + p);
        sx[p] = (v4f){TWO_K2E * px[0], TWO_K2E * px[1], TWO_K2E * px[2], 0.f};
        const float* py = y + 3 * (size_t)(base + p);
        sy[p] = (v4f){TWO_K2E * py[0], TWO_K2E * py[1], TWO_K2E * py[2], 0.f};
    }
    // ---- prologue: B0-init for own 128 columns ----
    if (tid < 128) {
        const int col = row0 + tid;
        const float* py = y + 3 * (size_t)(base + col);
        const float a = py[0], bb = py[1], c = py[2];
        DSTORE(&Bf[base + col], -K2E * (a*a + bb*bb + c*c));
    }

    // POST: entry barrier drains DSTOREs (compiler emits vmcnt(0) before
    // s_barrier), then tid0 release-stores the phase value.
    #define POSTH(pval) do { __syncthreads();                                   \
        if (tid == 0)                                                           \
            __hip_atomic_store(fb + q * 4, (pval), __ATOMIC_RELEASE,            \
                               __HIP_MEMORY_SCOPE_AGENT);                       \
    } while (0)

    POSTH(1);                         // B-init posted

    const int rr = ((lane & 1) << 2) | (lane & 2) | ((lane >> 2) & 1);
    float Aval = 0.f;

    for (int it = 0; it < NITERS; ++it) {
        // ---- f phase: duals = Bf (chunk k ready when flag[k] >= 2it+1) ----
        {
            float v1 = passH(sx, sy, Bf + base, sd, fb, 2 * it + 1,
                             rloc, lane, w, tid);
            Aval = LMU - __log2f(v1);
            if (lane < 8) DSTORE(&Af[base + rloc + rr], Aval);
        }
        POSTH(2 * it + 2);
        // ---- g phase: duals = Af (chunk k ready when flag[k] >= 2it+2) ----
        {
            float v1 = passH(sy, sx, Af + base, sd, fb, 2 * it + 2,
                             rloc, lane, w, tid);
            if (lane < 8)
                DSTORE(&Bf[base + rloc + rr], LMU - __log2f(v1));
        }
        POSTH(2 * it + 3);
    }
    // final: all blocks' Bf complete before epilogue reads it from LLC
    if (w == 0) {
        for (;;) {
            int vv = (lane < 16)
                ? __hip_atomic_load(fb + lane * 4, __ATOMIC_RELAXED,
                                    __HIP_MEMORY_SCOPE_AGENT)
                : 0x7fffffff;
            if (__ballot(vv >= 2 * NITERS + 1) == ~0ULL) break;
            __builtin_amdgcn_s_sleep(1);
        }
    }
    __syncthreads();

    // ---- epilogue: wave-owned 8 rows x full j ----
    {
        float s = epilA(sx, sy, Bf + base, Aval, rloc, 0, lane)
                + epilA(sx, sy, Bf + base, Aval, rloc, 1, lane);
        #pragma unroll
        for (int m = 32; m > 0; m >>= 1) s += __shfl_xor(s, m, 64);
        if (lane == 0) wsum[w] = s;
        __syncthreads();
        if (tid == 0) {
            float t = 0.f;
            #pragma unroll
            for (int i = 0; i < 16; ++i) t += wsum[i];
            atomicAdd(out, t * (1.0f / (float)BB));
        }
    }
    #undef POSTH
}

// =============== verified R11 kernel (2337 us) as launch fallback ===============
__global__ __launch_bounds__(1024, 4) void emd_sinkhornU(
    const float* __restrict__ x, const float* __restrict__ y,
    float* __restrict__ Af, float* __restrict__ Bf,
    int* __restrict__ flags, float* __restrict__ out)
{
    extern __shared__ float S[];     // 72 KB
    __shared__ float wsum[16];

    const int tid  = threadIdx.x;
    const int lane = tid & 63;
    const int w    = tid >> 6;
    const int blk  = blockIdx.x;
    const int b    = blk >> 4;
    const int q    = blk & 15;
    const int base = b * NN;
    const int row0 = q * 128;
    const int rloc = row0 + w * 8;
    int* fb = flags + 2048 + b * 64;  // upper flag region

    v4f   *sy = (v4f*)S;
    v4f   *sx = (v4f*)S + NN;
    float *sd = (float*)((v4f*)S + 2 * NN);

    #pragma unroll
    for (int v = 0; v < 2; ++v) {
        const int p = tid + (v << 10);
        const float* px = x + 3 * (size_t)(base + p);
        sx[p] = (v4f){TWO_K2E * px[0], TWO_K2E * px[1], TWO_K2E * px[2], 0.f};
        const float* py = y + 3 * (size_t)(base + p);
        sy[p] = (v4f){TWO_K2E * py[0], TWO_K2E * py[1], TWO_K2E * py[2], 0.f};
    }
    if (tid < 128) {
        const int col = row0 + tid;
        const float* py = y + 3 * (size_t)(base + col);
        const float a = py[0], bb = py[1], c = py[2];
        DSTORE(&Bf[base + col], -K2E * (a*a + bb*bb + c*c));
    }
    __syncthreads();
    if (tid == 0)
        __hip_atomic_store(fb + q * 4, 1, __ATOMIC_RELEASE, __HIP_MEMORY_SCOPE_AGENT);

    #define WAITB2(tgt) do { __syncthreads();                                   \
        if (w == 0) {                                                           \
            for (;;) {                                                          \
                int vv = (lane < 16)                                            \
                    ? __hip_atomic_load(fb + lane * 4, __ATOMIC_RELAXED,        \
                                        __HIP_MEMORY_SCOPE_AGENT)               \
                    : 0x7fffffff;                                               \
                if (__ballot(vv >= (tgt)) == ~0ULL) break;                      \
                __builtin_amdgcn_s_sleep(1);                                    \
            }                                                                   \
        }                                                                       \
        __syncthreads(); } while (0)

    #define POSTB2(pval) do { __syncthreads();                                  \
        if (tid == 0)                                                           \
            __hip_atomic_store(fb + q * 4, (pval), __ATOMIC_RELEASE,            \
                               __HIP_MEMORY_SCOPE_AGENT);                       \
    } while (0)

    #define STAGE2(gsrc) do {                                                   \
        float t0_ = DLOAD((gsrc) + tid);                                        \
        float t1_ = DLOAD((gsrc) + tid + 1024);                                 \
        sd[tid] = t0_; sd[tid + 1024] = t1_;                                    \
        __syncthreads(); } while (0)

    WAITB2(1);

    const int rr = ((lane & 1) << 2) | (lane & 2) | ((lane >> 2) & 1);
    float Aval = 0.f;

    for (int it = 0; it < NITERS; ++it) {
        STAGE2(Bf + base);
        {
            float v1 = sumpassF(sx, sy, sd, rloc, lane);
            Aval = LMU - __log2f(v1);
            if (lane < 8) DSTORE(&Af[base + rloc + rr], Aval);
        }
        POSTB2(2 * it + 2);
        WAITB2(2 * it + 2);
        STAGE2(Af + base);
        {
            float v1 = sumpassF(sy, sx, sd, rloc, lane);
            if (lane < 8)
                DSTORE(&Bf[base + rloc + rr], LMU - __log2f(v1));
        }
        POSTB2(2 * it + 3);
        WAITB2(2 * it + 3);
    }

    {
        float s = epilA(sx, sy, Bf + base, Aval, rloc, 0, lane)
                + epilA(sx, sy, Bf + base, Aval, rloc, 1, lane);
        #pragma unroll
        for (int m = 32; m > 0; m >>= 1) s += __shfl_xor(s, m, 64);
        if (lane == 0) wsum[w] = s;
        __syncthreads();
        if (tid == 0) {
            float t = 0.f;
            #pragma unroll
            for (int i = 0; i < 16; ++i) t += wsum[i];
            atomicAdd(out, t * (1.0f / (float)BB));
        }
    }
    #undef WAITB2
    #undef POSTB2
    #undef STAGE2
}

extern "C" void kernel_launch(void* const* d_in, const int* in_sizes, int n_in,
                              void* d_out, int out_size, void* d_ws, size_t ws_size,
                              hipStream_t stream) {
    const float* x = (const float*)d_in[0];
    const float* y = (const float*)d_in[1];
    float* out = (float*)d_out;
    char* ws = (char*)d_ws;

    int*   flags = (int*)ws;                                 // 16 KB (H: lower 4 KB; U: upper)
    float* Af    = (float*)(ws + 16384);                     // 128 KB
    float* Bf    = (float*)(ws + 16384 + (size_t)BB*NN*sizeof(float));

    hipMemsetAsync(flags, 0, 16384, stream);
    hipMemsetAsync(out, 0, sizeof(float), stream);

    void* args[] = {(void*)&x, (void*)&y, (void*)&Af, (void*)&Bf,
                    (void*)&flags, (void*)&out};

    const size_t shmem = (size_t)(2 * NN * 4 + NN) * sizeof(float);  // 72 KB
    // Preferred: split-wait pipelined kernel.
    hipError_t eh = hipFuncSetAttribute((const void*)emd_sinkhornHK,
                        hipFuncAttributeMaxDynamicSharedMemorySize, (int)shmem);
    hipError_t e = (eh == hipSuccess)
        ? hipLaunchCooperativeKernel((const void*)emd_sinkhornHK,
                                     dim3(256), dim3(1024), args, shmem, stream)
        : hipErrorInvalidValue;
    if (e != hipSuccess) {
        // Fallback: verified R11 kernel (2337 us)
        hipError_t eu = hipFuncSetAttribute((const void*)emd_sinkhornU,
                            hipFuncAttributeMaxDynamicSharedMemorySize, (int)shmem);
        hipError_t e2 = (eu == hipSuccess)
            ? hipLaunchCooperativeKernel((const void*)emd_sinkhornU,
                                         dim3(256), dim3(1024), args, shmem, stream)
            : hipErrorInvalidValue;
        if (e2 != hipSuccess) {
            hipLaunchKernelGGL(emd_sinkhornU, dim3(256), dim3(1024), shmem,
                               stream, x, y, Af, Bf, flags, out);
        }
    }
}

// Round 16
// 2268.230 us; speedup vs baseline: 1.0404x; 1.0404x over previous
//
#include <hip/hip_runtime.h>

#define BB 16
#define NN 2048
#define NITERS 100

// k = log2(e)/eps, eps = 0.05
#define K2E      28.853900817779268f
#define TWO_K2E  57.707801635558536f
#define INV2K    0.017328679513998632f   // 1/(2k)
#define INV_K2E  0.034657359027997264f
#define INV4K    0.008664339756999316f   // 1/(4k)
#define LMU      (-11.0f)                // log2(1/2048)

#if __has_builtin(__builtin_amdgcn_exp2f)
#define EXP2F(x) __builtin_amdgcn_exp2f(x)
#else
#define EXP2F(x) exp2f(x)
#endif

typedef float v2f __attribute__((ext_vector_type(2)));
typedef float v4f __attribute__((ext_vector_type(4)));

// device-coherent (LLC-homed) accessors for the dual arrays
#define DSTORE(p, v) __hip_atomic_store((p), (v), __ATOMIC_RELAXED, __HIP_MEMORY_SCOPE_AGENT)
#define DLOAD(p)     __hip_atomic_load((p), __ATOMIC_RELAXED, __HIP_MEMORY_SCOPE_AGENT)

// verified multi-value butterfly: 8 partials -> full row-sum on lanes 0..7
// at row index rr = ((lane&1)<<2)|(lane&2)|((lane>>2)&1)
__device__ __forceinline__ float bfly8(const float acc[8], int lane) {
    const bool b0 = lane & 1, b1 = lane & 2, b2 = lane & 4;
    float v4[4], v2_[2], v1;
    #pragma unroll
    for (int i = 0; i < 4; ++i) {
        float recv = __shfl_xor(b0 ? acc[i] : acc[i+4], 1, 64);
        v4[i] = (b0 ? acc[i+4] : acc[i]) + recv;
    }
    #pragma unroll
    for (int i = 0; i < 2; ++i) {
        float recv = __shfl_xor(b1 ? v4[i] : v4[i+2], 2, 64);
        v2_[i] = (b1 ? v4[i+2] : v4[i]) + recv;
    }
    {
        float recv = __shfl_xor(b2 ? v2_[0] : v2_[1], 4, 64);
        v1 = (b2 ? v2_[1] : v2_[0]) + recv;
    }
    v1 += __shfl_xor(v1, 8, 64);
    v1 += __shfl_xor(v1, 16, 64);
    v1 += __shfl_xor(v1, 32, 64);
    return v1;
}

// R27 FUSED-DUAL full-j pass: identical math and s-order to the verified
// R11 pass (bit-identical: same dual bits, same summation order), but the
// dual rides in T[j].w — staged there per phase — so the inner loop issues
// ONE ds_read_b128 per s-iter instead of b128 + b32. Removes ~100M LDS ops
// (~250us of the shared per-CU LDS pipe) + 1 issue slot + 1 addr per s-iter.
__device__ __forceinline__ float sumpassW(
    const v4f* __restrict__ U, const v4f* __restrict__ T,
    int rloc, int lane)
{
    v2f xp0[4], xp1[4], xp2[4], acc2[4];
    #pragma unroll
    for (int p = 0; p < 4; ++p) {
        const v4f ua = U[rloc + 2*p];
        const v4f ub = U[rloc + 2*p + 1];
        xp0[p] = (v2f){ua.x * INV2K, ub.x * INV2K};
        xp1[p] = (v2f){ua.y * INV2K, ub.y * INV2K};
        xp2[p] = (v2f){ua.z * INV2K, ub.z * INV2K};
        acc2[p] = (v2f){0.f, 0.f};
    }
    #pragma unroll 4
    for (int s = 0; s < 32; ++s) {
        const int p = lane + (s << 6);
        const v4f t = T[p];                    // coords + dual in one b128
        const v2f a0v = (v2f){t.x, t.x}, a1v = (v2f){t.y, t.y};
        const v2f a2v = (v2f){t.z, t.z}, adv = (v2f){t.w, t.w};
        #pragma unroll
        for (int qq = 0; qq < 4; ++qq) {
            v2f d = __builtin_elementwise_fma(xp0[qq], a0v,
                    __builtin_elementwise_fma(xp1[qq], a1v,
                    __builtin_elementwise_fma(xp2[qq], a2v, adv)));
            acc2[qq] += (v2f){EXP2F(d.x), EXP2F(d.y)};
        }
    }
    float acc[8];
    #pragma unroll
    for (int p = 0; p < 4; ++p) { acc[2*p] = acc2[p].x; acc[2*p+1] = acc2[p].y; }
    return bfly8(acc, lane);   // lanes<8: full row-sum for row rloc + rr
}

// R11-verified FULL-J sum-pass with separate sd buffer (fallback kernel).
__device__ __forceinline__ float sumpassF(
    const v4f* __restrict__ U, const v4f* __restrict__ T,
    const float* __restrict__ sdv,
    int rloc, int lane)
{
    v2f xp0[4], xp1[4], xp2[4], acc2[4];
    #pragma unroll
    for (int p = 0; p < 4; ++p) {
        const v4f ua = U[rloc + 2*p];
        const v4f ub = U[rloc + 2*p + 1];
        xp0[p] = (v2f){ua.x * INV2K, ub.x * INV2K};
        xp1[p] = (v2f){ua.y * INV2K, ub.y * INV2K};
        xp2[p] = (v2f){ua.z * INV2K, ub.z * INV2K};
        acc2[p] = (v2f){0.f, 0.f};
    }
    #pragma unroll 4
    for (int s = 0; s < 32; ++s) {
        const int p = lane + (s << 6);
        const v4f t = T[p];
        const float ad = sdv[p];
        const v2f a0v = (v2f){t.x, t.x}, a1v = (v2f){t.y, t.y};
        const v2f a2v = (v2f){t.z, t.z}, adv = (v2f){ad, ad};
        #pragma unroll
        for (int qq = 0; qq < 4; ++qq) {
            v2f d = __builtin_elementwise_fma(xp0[qq], a0v,
                    __builtin_elementwise_fma(xp1[qq], a1v,
                    __builtin_elementwise_fma(xp2[qq], a2v, adv)));
            acc2[qq] += (v2f){EXP2F(d.x), EXP2F(d.y)};
        }
    }
    float acc[8];
    #pragma unroll
    for (int p = 0; p < 4; ++p) { acc[2*p] = acc2[p].x; acc[2*p+1] = acc2[p].y; }
    return bfly8(acc, lane);
}

// Epilogue partial: sum_j P_ij*C_ij, 8 rows x one j-half; AoS tables.
// Reads only t.x/t.y/t.z (the .w now holds stale duals — unused here;
// the B dual comes from gB via LLC as in all verified rounds). Wave-local.
__device__ __forceinline__ float epilA(
    const v4f* __restrict__ U, const v4f* __restrict__ T,
    const float* __restrict__ gB,
    float Aval, int rloc, int jh, int lane)
{
    const int jb = (jh << 10) + lane;
    float dv[16];
    #pragma unroll
    for (int s = 0; s < 16; ++s)
        dv[s] = DLOAD(gB + jb + (s << 6));

    float xr0[8], xr1[8], xr2[8], Ak[8], x2k[8];
    #pragma unroll
    for (int k = 0; k < 8; ++k) {
        const v4f u = U[rloc + k];
        xr0[k] = u.x * INV2K;
        xr1[k] = u.y * INV2K;
        xr2[k] = u.z * INV2K;
        const int src = ((k & 1) << 2) | (k & 2) | ((k >> 2) & 1);
        Ak[k]  = __shfl(Aval, src, 64);
        x2k[k] = K2E * (xr0[k]*xr0[k] + xr1[k]*xr1[k] + xr2[k]*xr2[k]);
    }
    float acc = 0.f;
    for (int s = 0; s < 16; ++s) {
        const v4f t = T[jb + (s << 6)];
        const float a0 = t.x, a1 = t.y, a2 = t.z, tb = dv[s];
        const float q2 = (a0*a0 + a1*a1 + a2*a2) * INV4K;   // k|y|^2
        #pragma unroll
        for (int k = 0; k < 8; ++k) {
            float d = fmaf(xr0[k], a0, fmaf(xr1[k], a1, fmaf(xr2[k], a2, tb)));
            float P = EXP2F(d + Ak[k]);                       // exp(logP)
            float C = fmaxf((x2k[k] + q2 - (d - tb)) * INV_K2E, 0.f);
            acc = fmaf(P, C, acc);
        }
    }
    return acc;
}

// R27: R11 geometry and sync verbatim (256 blocks x 1024 thr, batch=blk>>4,
// 128 rows/block, full-j waves, w0-poll PW) with duals FUSED into T[].w:
//   f phase: stage Bf duals -> sy[].w ; pass reads T=sy (coords+dual)
//   g phase: stage Af duals -> sx[].w ; pass reads T=sx
// No separate sd buffer: LDS 72 -> 64 KB. POSTB's entry barrier already
// orders all .w reads of the previous pass before the next overwrite.
__global__ __launch_bounds__(1024, 4) void emd_sinkhornW(
    const float* __restrict__ x, const float* __restrict__ y,
    float* __restrict__ Af, float* __restrict__ Bf,
    int* __restrict__ flags, float* __restrict__ out)
{
    extern __shared__ float S[];     // sy(32KB) | sx(32KB) = 64 KB
    __shared__ float wsum[16];

    const int tid  = threadIdx.x;
    const int lane = tid & 63;
    const int w    = tid >> 6;        // 0..15
    const int blk  = blockIdx.x;
    const int b    = blk >> 4;        // batch 0..15
    const int q    = blk & 15;        // row-slab within batch (128 rows)
    const int base = b * NN;
    const int row0 = q * 128;
    const int rloc = row0 + w * 8;    // wave-owned 8 rows
    int* fb = flags + b * 64;         // 16 slots x 16 B per batch

    v4f *sy = (v4f*)S;                // batch y (2k-scaled, AoS; .w = dual)
    v4f *sx = (v4f*)S + NN;           // batch x (.w = dual)

    // ---- prologue: stage 2k-scaled AoS tables for own batch ----
    #pragma unroll
    for (int v = 0; v < 2; ++v) {
        const int p = tid + (v << 10);
        const float* px = x + 3 * (size_t)(base + p);
        sx[p] = (v4f){TWO_K2E * px[0], TWO_K2E * px[1], TWO_K2E * px[2], 0.f};
        const float* py = y + 3 * (size_t)(base + p);
        sy[p] = (v4f){TWO_K2E * py[0], TWO_K2E * py[1], TWO_K2E * py[2], 0.f};
    }
    // ---- prologue: B0-init for own 128 columns ----
    if (tid < 128) {
        const int col = row0 + tid;
        const float* py = y + 3 * (size_t)(base + col);
        const float a = py[0], bb = py[1], c = py[2];
        DSTORE(&Bf[base + col], -K2E * (a*a + bb*bb + c*c));
    }
    __syncthreads();                  // drains table + B-init stores
    if (tid == 0)
        __hip_atomic_store(fb + q * 4, 1, __ATOMIC_RELEASE, __HIP_MEMORY_SCOPE_AGENT);

    // wait: all 16 blocks of own batch posted >= tgt (wave 0 polls)
    #define WAITB(tgt) do { __syncthreads();                                    \
        if (w == 0) {                                                           \
            for (;;) {                                                          \
                int vv = (lane < 16)                                            \
                    ? __hip_atomic_load(fb + lane * 4, __ATOMIC_RELAXED,        \
                                        __HIP_MEMORY_SCOPE_AGENT)               \
                    : 0x7fffffff;                                               \
                if (__ballot(vv >= (tgt)) == ~0ULL) break;                      \
                __builtin_amdgcn_s_sleep(1);                                    \
            }                                                                   \
        }                                                                       \
        __syncthreads(); } while (0)

    // post: entry barrier drains DSTOREs (compiler emits vmcnt(0) before
    // s_barrier), then tid0 release-stores the phase value.
    #define POSTB(pval) do { __syncthreads();                                   \
        if (tid == 0)                                                           \
            __hip_atomic_store(fb + q * 4, (pval), __ATOMIC_RELEASE,            \
                               __HIP_MEMORY_SCOPE_AGENT);                       \
    } while (0)

    // stage one dual array (LLC, coherent DLOAD) into dstT[].w
    #define STAGEW(dstT, gsrc) do {                                             \
        float t0_ = DLOAD((gsrc) + tid);                                        \
        float t1_ = DLOAD((gsrc) + tid + 1024);                                 \
        (dstT)[tid].w = t0_; (dstT)[tid + 1024].w = t1_;                        \
        __syncthreads(); } while (0)

    WAITB(1);                         // all B-inits of the batch visible

    const int rr = ((lane & 1) << 2) | (lane & 2) | ((lane >> 2) & 1);
    float Aval = 0.f;

    for (int it = 0; it < NITERS; ++it) {
        // ---- f phase: duals = Bf -> sy.w (complete per the wait passed) ----
        STAGEW(sy, Bf + base);
        {
            float v1 = sumpassW(sx, sy, rloc, lane);
            Aval = LMU - __log2f(v1);
            if (lane < 8) DSTORE(&Af[base + rloc + rr], Aval);
        }
        POSTB(2 * it + 2);
        WAITB(2 * it + 2);
        // ---- g phase: duals = Af -> sx.w ----
        STAGEW(sx, Af + base);
        {
            float v1 = sumpassW(sy, sx, rloc, lane);
            if (lane < 8)
                DSTORE(&Bf[base + rloc + rr], LMU - __log2f(v1));
        }
        POSTB(2 * it + 3);
        WAITB(2 * it + 3);
    }
    // last WAITB guarantees final Bf of the whole batch is complete

    // ---- epilogue: wave-owned 8 rows x full j ----
    {
        float s = epilA(sx, sy, Bf + base, Aval, rloc, 0, lane)
                + epilA(sx, sy, Bf + base, Aval, rloc, 1, lane);
        #pragma unroll
        for (int m = 32; m > 0; m >>= 1) s += __shfl_xor(s, m, 64);
        if (lane == 0) wsum[w] = s;
        __syncthreads();
        if (tid == 0) {
            float t = 0.f;
            #pragma unroll
            for (int i = 0; i < 16; ++i) t += wsum[i];
            atomicAdd(out, t * (1.0f / (float)BB));
        }
    }
    #undef WAITB
    #undef POSTB
    #undef STAGEW
}

// =============== verified R11 kernel (2337 us) as launch fallback ===============
__global__ __launch_bounds__(1024, 4) void emd_sinkhornU(
    const float* __restrict__ x, const float* __restrict__ y,
    float* __restrict__ Af, float* __restrict__ Bf,
    int* __restrict__ flags, float* __restrict__ out)
{
    extern __shared__ float S[];     // 72 KB
    __shared__ float wsum[16];

    const int tid  = threadIdx.x;
    const int lane = tid & 63;
    const int w    = tid >> 6;
    const int blk  = blockIdx.x;
    const int b    = blk >> 4;
    const int q    = blk & 15;
    const int base = b * NN;
    const int row0 = q * 128;
    const int rloc = row0 + w * 8;
    int* fb = flags + 2048 + b * 64;  // upper flag region

    v4f   *sy = (v4f*)S;
    v4f   *sx = (v4f*)S + NN;
    float *sd = (float*)((v4f*)S + 2 * NN);

    #pragma unroll
    for (int v = 0; v < 2; ++v) {
        const int p = tid + (v << 10);
        const float* px = x + 3 * (size_t)(base + p);
        sx[p] = (v4f){TWO_K2E * px[0], TWO_K2E * px[1], TWO_K2E * px[2], 0.f};
        const float* py = y + 3 * (size_t)(base + p);
        sy[p] = (v4f){TWO_K2E * py[0], TWO_K2E * py[1], TWO_K2E * py[2], 0.f};
    }
    if (tid < 128) {
        const int col = row0 + tid;
        const float* py = y + 3 * (size_t)(base + col);
        const float a = py[0], bb = py[1], c = py[2];
        DSTORE(&Bf[base + col], -K2E * (a*a + bb*bb + c*c));
    }
    __syncthreads();
    if (tid == 0)
        __hip_atomic_store(fb + q * 4, 1, __ATOMIC_RELEASE, __HIP_MEMORY_SCOPE_AGENT);

    #define WAITB2(tgt) do { __syncthreads();                                   \
        if (w == 0) {                                                           \
            for (;;) {                                                          \
                int vv = (lane < 16)                                            \
                    ? __hip_atomic_load(fb + lane * 4, __ATOMIC_RELAXED,        \
                                        __HIP_MEMORY_SCOPE_AGENT)               \
                    : 0x7fffffff;                                               \
                if (__ballot(vv >= (tgt)) == ~0ULL) break;                      \
                __builtin_amdgcn_s_sleep(1);                                    \
            }                                                                   \
        }                                                                       \
        __syncthreads(); } while (0)

    #define POSTB2(pval) do { __syncthreads();                                  \
        if (tid == 0)                                                           \
            __hip_atomic_store(fb + q * 4, (pval), __ATOMIC_RELEASE,            \
                               __HIP_MEMORY_SCOPE_AGENT);                       \
    } while (0)

    #define STAGE2(gsrc) do {                                                   \
        float t0_ = DLOAD((gsrc) + tid);                                        \
        float t1_ = DLOAD((gsrc) + tid + 1024);                                 \
        sd[tid] = t0_; sd[tid + 1024] = t1_;                                    \
        __syncthreads(); } while (0)

    WAITB2(1);

    const int rr = ((lane & 1) << 2) | (lane & 2) | ((lane >> 2) & 1);
    float Aval = 0.f;

    for (int it = 0; it < NITERS; ++it) {
        STAGE2(Bf + base);
        {
            float v1 = sumpassF(sx, sy, sd, rloc, lane);
            Aval = LMU - __log2f(v1);
            if (lane < 8) DSTORE(&Af[base + rloc + rr], Aval);
        }
        POSTB2(2 * it + 2);
        WAITB2(2 * it + 2);
        STAGE2(Af + base);
        {
            float v1 = sumpassF(sy, sx, sd, rloc, lane);
            if (lane < 8)
                DSTORE(&Bf[base + rloc + rr], LMU - __log2f(v1));
        }
        POSTB2(2 * it + 3);
        WAITB2(2 * it + 3);
    }

    {
        float s = epilA(sx, sy, Bf + base, Aval, rloc, 0, lane)
                + epilA(sx, sy, Bf + base, Aval, rloc, 1, lane);
        #pragma unroll
        for (int m = 32; m > 0; m >>= 1) s += __shfl_xor(s, m, 64);
        if (lane == 0) wsum[w] = s;
        __syncthreads();
        if (tid == 0) {
            float t = 0.f;
            #pragma unroll
            for (int i = 0; i < 16; ++i) t += wsum[i];
            atomicAdd(out, t * (1.0f / (float)BB));
        }
    }
    #undef WAITB2
    #undef POSTB2
    #undef STAGE2
}

extern "C" void kernel_launch(void* const* d_in, const int* in_sizes, int n_in,
                              void* d_out, int out_size, void* d_ws, size_t ws_size,
                              hipStream_t stream) {
    const float* x = (const float*)d_in[0];
    const float* y = (const float*)d_in[1];
    float* out = (float*)d_out;
    char* ws = (char*)d_ws;

    int*   flags = (int*)ws;                                 // 16 KB (W: lower 4 KB; U: upper)
    float* Af    = (float*)(ws + 16384);                     // 128 KB
    float* Bf    = (float*)(ws + 16384 + (size_t)BB*NN*sizeof(float));

    hipMemsetAsync(flags, 0, 16384, stream);
    hipMemsetAsync(out, 0, sizeof(float), stream);

    void* args[] = {(void*)&x, (void*)&y, (void*)&Af, (void*)&Bf,
                    (void*)&flags, (void*)&out};

    // Preferred: fused-dual kernel (64 KB LDS, one b128/s-iter).
    const size_t shmemW = (size_t)2 * NN * 4 * sizeof(float);   // 64 KB
    hipError_t ew = hipFuncSetAttribute((const void*)emd_sinkhornW,
                        hipFuncAttributeMaxDynamicSharedMemorySize, (int)shmemW);
    hipError_t e = (ew == hipSuccess)
        ? hipLaunchCooperativeKernel((const void*)emd_sinkhornW,
                                     dim3(256), dim3(1024), args, shmemW, stream)
        : hipErrorInvalidValue;
    if (e != hipSuccess) {
        // Fallback: verified R11 kernel (2337 us, 72 KB LDS)
        const size_t shmemU = (size_t)(2 * NN * 4 + NN) * sizeof(float);
        hipError_t eu = hipFuncSetAttribute((const void*)emd_sinkhornU,
                            hipFuncAttributeMaxDynamicSharedMemorySize, (int)shmemU);
        hipError_t e2 = (eu == hipSuccess)
            ? hipLaunchCooperativeKernel((const void*)emd_sinkhornU,
                                         dim3(256), dim3(1024), args, shmemU, stream)
            : hipErrorInvalidValue;
        if (e2 != hipSuccess) {
            hipLaunchKernelGGL(emd_sinkhornU, dim3(256), dim3(1024), shmemU,
                               stream, x, y, Af, Bf, flags, out);
        }
    }
}